// Round 7
// baseline (568.713 us; speedup 1.0000x reference)
//
#include <hip/hip_runtime.h>
#include <math.h>

#define DDIM 256
#define NSPLIT 4
#define TILES_PER_SPLIT 16   // 16 tiles x 32 codes = 512 codes per split
#define TILE_CODES 32
#define TILE_BYTES 16384     // 32 codes x 256 dims x 2B (panel layout)
#define ROWS_PER_BLOCK 64    // 4 waves x 16 rows

typedef __attribute__((ext_vector_type(8))) short short8v;
typedef __attribute__((ext_vector_type(4))) float float4v;
typedef unsigned int u32;
typedef unsigned short u16;

// ---- RNE float -> bf16 ----
__device__ __forceinline__ short f2bf(float x) {
    u32 u = __float_as_uint(x);
    u = u + 0x7fffu + ((u >> 16) & 1u);
    return (short)(u >> 16);
}

// ---- async global->LDS, 16B per lane; lds dst = wave-uniform base + lane*16 ----
__device__ __forceinline__ void gload_lds16(const void* g, void* l) {
    __builtin_amdgcn_global_load_lds(
        (const __attribute__((address_space(1))) u32*)g,
        (__attribute__((address_space(3))) u32*)l, 16, 0, 0);
}

// ---- numpy pairwise-sum simulation (bit-faithful for n=256 contiguous) ----
__device__ __forceinline__ float np_sq_chain(const float* v, int lane) {
    #pragma clang fp contract(off)
    const int half = lane >> 3, j = lane & 7;
    const float* base = v + half * 128 + j;
    float x = base[0];
    float c = x * x;
    #pragma unroll
    for (int m = 1; m < 16; ++m) {
        float y = base[8 * m];
        float s = y * y;
        c = c + s;
    }
    return c;
}

__device__ __forceinline__ float np_combine16(const float* c) {
    #pragma clang fp contract(off)
    float L = ((c[0] + c[1]) + (c[2] + c[3])) + ((c[4] + c[5]) + (c[6] + c[7]));
    float R = ((c[8] + c[9]) + (c[10] + c[11])) + ((c[12] + c[13]) + (c[14] + c[15]));
    return L + R;
}

// ---- top-3 insertion (strict <, preserves first-insertion on ties) ----
__device__ __forceinline__ void ins3(float m, int k,
                                     float& v0, float& v1, float& v2,
                                     int& i0, int& i1, int& i2) {
    if (m < v0)      { v2 = v1; i2 = i1; v1 = v0; i1 = i0; v0 = m; i0 = k; }
    else if (m < v1) { v2 = v1; i2 = i1; v1 = m;  i1 = k; }
    else if (m < v2) { v2 = m;  i2 = k; }
}

// ---------------- kernel 1: zero counts ----------------
__global__ void zero_counts_kernel(int* __restrict__ counts, int K) {
    int i = blockIdx.x * 256 + threadIdx.x;
    if (i < K) counts[i] = 0;
}

// ---------------- kernel 2: numpy-faithful code norms ||e_k||^2 ----------------
__global__ void code_norms_np_kernel(const float* __restrict__ e, float* __restrict__ e2) {
    __shared__ float buf[DDIM];
    __shared__ float ch[16];
    int k = blockIdx.x;
    int t = threadIdx.x;  // 64 threads = 1 wave
    float4 v = *(const float4*)&e[(size_t)k * DDIM + t * 4];
    *(float4*)&buf[t * 4] = v;
    __syncthreads();
    if (t < 16) ch[t] = np_sq_chain(buf, t);
    __syncthreads();
    if (t == 0) e2[k] = np_combine16(ch);
}

// ---------------- kernel 2b: convert e -> bf16 panel layout ----------------
// ebf_p[tile=k/32][d8=0..31][r=k%32][8 shorts]; tile = 16KB contiguous.
__global__ void convert_permute_e_kernel(const float* __restrict__ e, char* __restrict__ ebf_p) {
    int id = blockIdx.x * 256 + threadIdx.x;   // id = k*32 + d8, total K*32
    int k = id >> 5, d8 = id & 31;
    const float* s = &e[(size_t)k * DDIM + d8 * 8];
    float4 f0 = *(const float4*)s;
    float4 f1 = *(const float4*)(s + 4);
    short8v v;
    v[0] = f2bf(f0.x); v[1] = f2bf(f0.y); v[2] = f2bf(f0.z); v[3] = f2bf(f0.w);
    v[4] = f2bf(f1.x); v[5] = f2bf(f1.y); v[6] = f2bf(f1.z); v[7] = f2bf(f1.w);
    *(short8v*)(ebf_p + ((size_t)(k >> 5) << 14) + d8 * 512 + (k & 31) * 16) = v;
}

// ---------------- kernel 3: zero-persistent-operand MFMA candidate kernel ----------------
// SCRATCH-ELIMINATION (round 6 resubmit; round-6 bench was an infra failure,
// the discriminator was never measured). Diagnosis from rounds 0-5: the
// compiler NEVER keeps the persistent short8v zf[] operand arrays in
// registers -- every variant spilled them to HBM-backed scratch
// (WRITE_SIZE/threads = 134-432 B ~= sizeof(zf)+temps in all 5 rounds;
// VGPR_Count pinned at the budget while demand exceeded it; waves_per_eu(2,4)
// request was ignored). The scratch reloads sit serially in the MFMA operand
// chain (~16 scattered reloads/tile at ~2.5kcy under contention = the
// unexplained ~40kcy/tile), which is why sync/occupancy/dataflow changes were
// all neutral.
// Fix: NO persistent operand registers. Each wave's 16 z-rows are staged once
// into a private 8KB LDS panel (same layout & f2bf as the zf fragments ->
// bit-identical scores); the kk-loop reads a0,a1 (codes) and zb (z) from LDS
// transiently: 3 ds_read_b128 + 2 MFMA per kk, peak live ~45 regs, only the
// top-3 (12 regs) persists across tiles. Codes keep the round-1 verified
// gload_lds double-buffer + counted vmcnt(4) ledger.
// LDS: 32KB dbuf + 32KB z panels + 2KB e2 = 66KB -> 2 blocks/CU.
// Falsifiable: WRITE_SIZE must collapse 113MB -> <8MB (scratch gone).
__global__ __attribute__((amdgpu_flat_work_group_size(256, 256)))
void vq_cand_kernel(const float* __restrict__ z, const char* __restrict__ ebf_p,
                    const float* __restrict__ e2, float* __restrict__ cand_v,
                    u16* __restrict__ cand_i, int N) {
    __shared__ __align__(16) char smem[2][TILE_BYTES];   // 32 KB code dbuf
    __shared__ __align__(16) char zlds[4][8192];         // 32 KB z panels (per wave)
    __shared__ float e2s[512];
    const int t    = threadIdx.x;
    const int w    = t >> 6;
    const int lane = t & 63;
    const int quad = lane >> 4;
    const int l15  = lane & 15;
    const int s    = blockIdx.y;
    const int rw0  = blockIdx.x * ROWS_PER_BLOCK + w * 16;   // this wave's 16 rows

    const char* tile_base = ebf_p + (size_t)s * TILES_PER_SPLIT * TILE_BYTES;

    // 2-deep prefetch: T0 -> buf0, T1 -> buf1 (256 thr x 16B = 4KB/call)
    {
        const char* src0 = tile_base + w * 4096 + lane * 16;
        char* dst0 = smem[0] + w * 4096;
        char* dst1 = smem[1] + w * 4096;
        #pragma unroll
        for (int q = 0; q < 4; ++q) gload_lds16(src0 + q * 1024, dst0 + q * 1024);
        #pragma unroll
        for (int q = 0; q < 4; ++q) gload_lds16(src0 + TILE_BYTES + q * 1024, dst1 + q * 1024);
    }

    // e2 for this split -> LDS once
    e2s[t]       = e2[s * 512 + t];
    e2s[t + 256] = e2[s * 512 + t + 256];

    // ---- stage this wave's 16 z-rows into its private LDS panel ----
    // zlds[w][c=dim8][r=row][16B]: lane(quad,l15) at step c2 handles
    // c = c2*4+quad for row l15 -> zb read below is bit-identical to the
    // old zf[kk] fragment (z[rw0+l15][kk*32+quad*8 .. +8], RNE bf16).
    {
        char* zw = zlds[w];
        const float* zr = &z[(size_t)(rw0 + l15) * DDIM];
        #pragma unroll
        for (int c2 = 0; c2 < 8; ++c2) {
            int c = c2 * 4 + quad;
            float4 f0 = *(const float4*)&zr[c * 8];
            float4 f1 = *(const float4*)&zr[c * 8 + 4];
            short8v v;
            v[0] = f2bf(f0.x); v[1] = f2bf(f0.y); v[2] = f2bf(f0.z); v[3] = f2bf(f0.w);
            v[4] = f2bf(f1.x); v[5] = f2bf(f1.y); v[6] = f2bf(f1.z); v[7] = f2bf(f1.w);
            *(short8v*)(zw + c * 256 + l15 * 16) = v;
        }
    }

    float v0 = 3.4e38f, v1 = 3.4e38f, v2 = 3.4e38f;
    int   i0 = 0x7fff,  i1 = 0x7fff,  i2 = 0x7fff;

    // z-panel + e2s ds_writes drained; align all waves before tile 0
    asm volatile("s_waitcnt lgkmcnt(0)" ::: "memory");

    const char* zw = zlds[w];

    // vmcnt ledger (4 gload_lds per tile): steady-state outstanding entering
    // iter tt = {T(tt):4, T(tt+1):4} -> vmcnt(4) completes T(tt); the z/e2
    // global loads were drained pre-loop (their uses force FIFO waits that
    // also cover T0/T1). Last iter waits 0.
    #pragma unroll 1
    for (int tt = 0; tt < TILES_PER_SPLIT; ++tt) {
        if (tt < TILES_PER_SPLIT - 1)
            asm volatile("s_waitcnt vmcnt(4)" ::: "memory");
        else
            asm volatile("s_waitcnt vmcnt(0)" ::: "memory");
        __builtin_amdgcn_s_barrier();   // everyone's tile-tt data is in LDS

        const char* es = smem[tt & 1];
        const int kloc  = tt * TILE_CODES;
        const int kbase = s * 512 + kloc;
        float4 e2a = *(const float4*)&e2s[kloc + quad * 4];
        float4 e2b = *(const float4*)&e2s[kloc + 16 + quad * 4];

        float4v acc0 = (float4v)0.0f, acc1 = (float4v)0.0f;

        #pragma unroll
        for (int kk = 0; kk < 8; ++kk) {
            int c = kk * 4 + quad;  // d8 chunk
            short8v a0 = *(const short8v*)(es + c * 512 + l15 * 16);        // codes 0..15
            short8v a1 = *(const short8v*)(es + c * 512 + (16 + l15) * 16); // codes 16..31
            short8v zb = *(const short8v*)(zw + c * 256 + l15 * 16);        // z rows 0..15
            acc0 = __builtin_amdgcn_mfma_f32_16x16x32_bf16(a0, zb, acc0, 0, 0, 0);
            acc1 = __builtin_amdgcn_mfma_f32_16x16x32_bf16(a1, zb, acc1, 0, 0, 0);
        }

        // epilogue: fold tile scores m(k)=e2[k]-2S into per-row top-3
        // (same per-row code visit order as rounds 0-5 -> bit-identical)
        float m;
        m = fmaf(-2.0f, acc0[0], e2a.x); ins3(m, kbase + quad * 4 + 0,      v0, v1, v2, i0, i1, i2);
        m = fmaf(-2.0f, acc1[0], e2b.x); ins3(m, kbase + 16 + quad * 4 + 0, v0, v1, v2, i0, i1, i2);
        m = fmaf(-2.0f, acc0[1], e2a.y); ins3(m, kbase + quad * 4 + 1,      v0, v1, v2, i0, i1, i2);
        m = fmaf(-2.0f, acc1[1], e2b.y); ins3(m, kbase + 16 + quad * 4 + 1, v0, v1, v2, i0, i1, i2);
        m = fmaf(-2.0f, acc0[2], e2a.z); ins3(m, kbase + quad * 4 + 2,      v0, v1, v2, i0, i1, i2);
        m = fmaf(-2.0f, acc1[2], e2b.z); ins3(m, kbase + 16 + quad * 4 + 2, v0, v1, v2, i0, i1, i2);
        m = fmaf(-2.0f, acc0[3], e2a.w); ins3(m, kbase + quad * 4 + 3,      v0, v1, v2, i0, i1, i2);
        m = fmaf(-2.0f, acc1[3], e2b.w); ins3(m, kbase + 16 + quad * 4 + 3, v0, v1, v2, i0, i1, i2);

        // all waves done READING buf[tt&1] before anyone refills it
        asm volatile("s_waitcnt lgkmcnt(0)" ::: "memory");
        __builtin_amdgcn_s_barrier();

        if (tt + 2 < TILES_PER_SPLIT) {
            const char* src = tile_base + (size_t)(tt + 2) * TILE_BYTES + w * 4096 + lane * 16;
            char* dst = smem[tt & 1] + w * 4096;
            #pragma unroll
            for (int q = 0; q < 4; ++q) gload_lds16(src + q * 1024, dst + q * 1024);
        }
    }

    // ---- cross-quad merge via shuffles: 4 quads x top-3 -> split top-3 ----
    {
        float bm0 = 3.4e38f, bm1 = 3.4e38f, bm2 = 3.4e38f;
        int   bk0 = 0x7fff,  bk1 = 0x7fff,  bk2 = 0x7fff;
        #pragma unroll
        for (int q = 0; q < 4; ++q) {
            int src = l15 + q * 16;
            float m0 = __shfl(v0, src); int k0 = __shfl(i0, src);
            float m1 = __shfl(v1, src); int k1 = __shfl(i1, src);
            float m2 = __shfl(v2, src); int k2 = __shfl(i2, src);
            ins3(m0, k0, bm0, bm1, bm2, bk0, bk1, bk2);
            ins3(m1, k1, bm0, bm1, bm2, bk0, bk1, bk2);
            ins3(m2, k2, bm0, bm1, bm2, bk0, bk1, bk2);
        }
        // split-major layout cand[s][n][3]: contiguous per-block writes
        if (quad == 0) {
            size_t base = ((size_t)s * N + (rw0 + l15)) * 3;
            cand_v[base]     = bm0;  cand_i[base]     = (u16)bk0;
            cand_v[base + 1] = bm1;  cand_i[base + 1] = (u16)bk1;
            cand_v[base + 2] = bm2;  cand_i[base + 2] = (u16)bk2;
        }
    }
}

// ---------------- kernel 4: prefilter + np-faithful re-rank + gather + loss ----------------
// One wave per row. Prefilter 12 bf16-scored candidates -> top-6, exact fp64
// dots on 6, numpy-fp32-faithful distance ranking, fused gather + partials.
__global__ void refine_fused_kernel(const float* __restrict__ z, const float* __restrict__ e,
                                    const float* __restrict__ e2np,
                                    const float* __restrict__ cand_v,
                                    const u16* __restrict__ cand_i,
                                    int* __restrict__ counts, float* __restrict__ partials,
                                    float* __restrict__ out_zq, float* __restrict__ out_idx,
                                    int N) {
    __shared__ float buf[4][DDIM];
    __shared__ float ch[4][16];
    __shared__ float wsum[4];
    const int w = threadIdx.x >> 6;
    const int t = threadIdx.x & 63;
    const int n = blockIdx.x * 4 + w;

    float4 zv = *(const float4*)&z[(size_t)n * DDIM + t * 4];
    *(float4*)&buf[w][t * 4] = zv;
    __syncthreads();
    if (t < 16) ch[w][t] = np_sq_chain(buf[w], t);
    __syncthreads();

    // ---- prefilter: 12 -> top-6 by bf16 score (uniform across wave) ----
    // read order sp=0..3, j=0..2 matches the original n*12+c order exactly
    float bv[6]; int bi[6];
    #pragma unroll
    for (int c = 0; c < 6; ++c) { bv[c] = 3.4e38f; bi[c] = 0x7fffffff; }
    #pragma unroll
    for (int c = 0; c < 12; ++c) {
        int sp = c / 3, j = c - sp * 3;
        size_t off = ((size_t)sp * N + n) * 3 + j;
        float v  = cand_v[off];
        int   id = (int)cand_i[off];
        #pragma unroll
        for (int x = 0; x < 6; ++x) {
            if (v < bv[x] || (v == bv[x] && id < bi[x])) {
                for (int d = 5; d > x; --d) { bv[d] = bv[d - 1]; bi[d] = bi[d - 1]; }
                bv[x] = v; bi[x] = id;
                break;
            }
        }
    }

    float dotf[6];
    #pragma unroll
    for (int c = 0; c < 6; ++c) {
        int k = bi[c];
        float4 ev = *(const float4*)&e[(size_t)k * DDIM + t * 4];
        double p = (double)zv.x * (double)ev.x + (double)zv.y * (double)ev.y
                 + (double)zv.z * (double)ev.z + (double)zv.w * (double)ev.w;
        #pragma unroll
        for (int o = 32; o > 0; o >>= 1) p += __shfl_down(p, o);
        dotf[c] = (float)p;   // correctly-rounded fp32 of exact dot
    }

    int bk = 0;
    if (t == 0) {
        #pragma clang fp contract(off)
        float sx = np_combine16(ch[w]);
        float bd = 3.4e38f;
        bk = 0x7fffffff;
        #pragma unroll
        for (int c = 0; c < 6; ++c) {
            float twod = 2.0f * dotf[c];
            float t1 = sx - twod;
            float d2v = t1 + e2np[bi[c]];
            d2v = fmaxf(d2v, 0.0f);
            float d = sqrtf(d2v);
            if (d < bd || (d == bd && bi[c] < bk)) { bd = d; bk = bi[c]; }
        }
    }
    int wk = __shfl(bk, 0);

    float4 ev = *(const float4*)&e[(size_t)wk * DDIM + t * 4];
    *(float4*)&out_zq[(size_t)n * DDIM + t * 4] = ev;
    float dx = zv.x - ev.x, dy = zv.y - ev.y, dz = zv.z - ev.z, dw = zv.w - ev.w;
    float sq = dx * dx + dy * dy + dz * dz + dw * dw;
    #pragma unroll
    for (int o = 32; o > 0; o >>= 1) sq += __shfl_down(sq, o);
    if (t == 0) {
        wsum[w] = sq;
        atomicAdd(&counts[wk], 1);
        out_idx[n] = (float)wk;
    }
    __syncthreads();
    if (threadIdx.x == 0)
        partials[blockIdx.x] = wsum[0] + wsum[1] + wsum[2] + wsum[3];
}

// ---------------- kernel 5: finalize loss ----------------
__global__ void finalize_kernel(const int* __restrict__ counts, const float* __restrict__ partials,
                                float* __restrict__ out_loss, int K, int NB,
                                float invN, float invND) {
    int t = threadIdx.x;
    double ent = 0.0, sq = 0.0;
    for (int k = t; k < K; k += 256) {
        float p = (float)counts[k] * invN;
        ent += (double)(p * logf(p + 1e-10f));
    }
    for (int i = t; i < NB; i += 256) sq += (double)partials[i];
    #pragma unroll
    for (int o = 32; o > 0; o >>= 1) {
        ent += __shfl_down(ent, o);
        sq  += __shfl_down(sq, o);
    }
    __shared__ double e4[4], s4[4];
    if ((t & 63) == 0) { e4[t >> 6] = ent; s4[t >> 6] = sq; }
    __syncthreads();
    if (t == 0) {
        double esum = e4[0] + e4[1] + e4[2] + e4[3];
        double ssum = s4[0] + s4[1] + s4[2] + s4[3];
        float perp = expf((float)(-esum));
        float mean = (float)ssum * invND;
        out_loss[0] = 1.25f * mean - 0.01f * perp;
    }
}

extern "C" void kernel_launch(void* const* d_in, const int* in_sizes, int n_in,
                              void* d_out, int out_size, void* d_ws, size_t ws_size,
                              hipStream_t stream) {
    const float* z = (const float*)d_in[0];
    const float* e = (const float*)d_in[1];
    const int N = in_sizes[0] / DDIM;   // 32768
    const int K = in_sizes[1] / DDIM;   // 2048

    float* out      = (float*)d_out;
    float* out_zq   = out;
    float* out_loss = out + (size_t)N * DDIM;
    float* out_idx  = out_loss + 1;

    // ws layout (bytes):
    //   counts[K]            @ 0        (8 KB)
    //   e2np[K]              @ 8192     (8 KB)
    //   partials[N/4]        @ 16384    (32 KB)
    //   cand_v[4][N][3] f32  @ 49152    (1.5 MB)
    //   cand_i[4][N][3] u16  @ 1622016  (768 KB)
    //   ebf_p (1 MB panels)  @ 2408448  -> total ~3.46 MB
    int*   counts   = (int*)d_ws;
    float* e2np     = (float*)((char*)d_ws + 8192);
    float* partials = (float*)((char*)d_ws + 16384);
    float* cand_v   = (float*)((char*)d_ws + 49152);
    u16*   cand_i   = (u16*)((char*)d_ws + 1622016);
    char*  ebf_p    = (char*)d_ws + 2408448;

    zero_counts_kernel<<<(K + 255) / 256, 256, 0, stream>>>(counts, K);
    code_norms_np_kernel<<<K, 64, 0, stream>>>(e, e2np);
    convert_permute_e_kernel<<<K * 32 / 256, 256, 0, stream>>>(e, ebf_p);
    vq_cand_kernel<<<dim3(N / ROWS_PER_BLOCK, NSPLIT), 256, 0, stream>>>(z, ebf_p, e2np,
                                                                         cand_v, cand_i, N);
    refine_fused_kernel<<<N / 4, 256, 0, stream>>>(z, e, e2np, cand_v, cand_i,
                                                   counts, partials, out_zq, out_idx, N);
    finalize_kernel<<<1, 256, 0, stream>>>(counts, partials, out_loss, K, N / 4,
                                           1.0f / (float)N, 1.0f / (float)(N * DDIM));
}

// Round 8
// 404.390 us; speedup vs baseline: 1.4063x; 1.4063x over previous
//
#include <hip/hip_runtime.h>
#include <math.h>

#define DDIM 256
#define NSPLIT 2
#define TILES_PER_SPLIT 32   // 32 tiles x 32 codes = 1024 codes per split
#define TILE_CODES 32
#define TILE_BYTES 16384     // 32 codes x 256 dims x 2B (panel layout)
#define ROWS_PER_BLOCK 128   // 8 waves x 16 rows

typedef __attribute__((ext_vector_type(8))) short short8v;
typedef __attribute__((ext_vector_type(4))) float float4v;
typedef unsigned int u32;
typedef unsigned short u16;

// ---- RNE float -> bf16 ----
__device__ __forceinline__ short f2bf(float x) {
    u32 u = __float_as_uint(x);
    u = u + 0x7fffu + ((u >> 16) & 1u);
    return (short)(u >> 16);
}

// ---- numpy pairwise-sum simulation (bit-faithful for n=256 contiguous) ----
__device__ __forceinline__ float np_sq_chain(const float* v, int lane) {
    #pragma clang fp contract(off)
    const int half = lane >> 3, j = lane & 7;
    const float* base = v + half * 128 + j;
    float x = base[0];
    float c = x * x;
    #pragma unroll
    for (int m = 1; m < 16; ++m) {
        float y = base[8 * m];
        float s = y * y;
        c = c + s;
    }
    return c;
}

__device__ __forceinline__ float np_combine16(const float* c) {
    #pragma clang fp contract(off)
    float L = ((c[0] + c[1]) + (c[2] + c[3])) + ((c[4] + c[5]) + (c[6] + c[7]));
    float R = ((c[8] + c[9]) + (c[10] + c[11])) + ((c[12] + c[13]) + (c[14] + c[15]));
    return L + R;
}

// ---- top-3 insertion (strict <, preserves first-insertion on ties) ----
__device__ __forceinline__ void ins3(float m, int k,
                                     float& v0, float& v1, float& v2,
                                     int& i0, int& i1, int& i2) {
    if (m < v0)      { v2 = v1; i2 = i1; v1 = v0; i1 = i0; v0 = m; i0 = k; }
    else if (m < v1) { v2 = v1; i2 = i1; v1 = m;  i1 = k; }
    else if (m < v2) { v2 = m;  i2 = k; }
}

// ---------------- kernel 2: numpy-faithful code norms ||e_k||^2 (+ zero counts) ----------------
__global__ void code_norms_np_kernel(const float* __restrict__ e, float* __restrict__ e2,
                                     int* __restrict__ counts) {
    __shared__ float buf[DDIM];
    __shared__ float ch[16];
    int k = blockIdx.x;
    int t = threadIdx.x;  // 64 threads = 1 wave
    if (t == 0) counts[k] = 0;   // fused zero_counts (grid == K)
    float4 v = *(const float4*)&e[(size_t)k * DDIM + t * 4];
    *(float4*)&buf[t * 4] = v;
    __syncthreads();
    if (t < 16) ch[t] = np_sq_chain(buf, t);
    __syncthreads();
    if (t == 0) e2[k] = np_combine16(ch);
}

// ---------------- kernel 2b: convert e -> bf16 panel layout ----------------
// ebf_p[tile=k/32][d8=0..31][r=k%32][8 shorts]; tile = 16KB contiguous.
__global__ void convert_permute_e_kernel(const float* __restrict__ e, char* __restrict__ ebf_p) {
    int id = blockIdx.x * 256 + threadIdx.x;   // id = k*32 + d8, total K*32
    int k = id >> 5, d8 = id & 31;
    const float* s = &e[(size_t)k * DDIM + d8 * 8];
    float4 f0 = *(const float4*)s;
    float4 f1 = *(const float4*)(s + 4);
    short8v v;
    v[0] = f2bf(f0.x); v[1] = f2bf(f0.y); v[2] = f2bf(f0.z); v[3] = f2bf(f0.w);
    v[4] = f2bf(f1.x); v[5] = f2bf(f1.y); v[6] = f2bf(f1.z); v[7] = f2bf(f1.w);
    *(short8v*)(ebf_p + ((size_t)(k >> 5) << 14) + d8 * 512 + (k & 31) * 16) = v;
}

// ---------------- kernel 3: barrier-free L2-streaming MFMA candidate kernel ----------------
// INDEPENDENT-STREAM MAXIMIZATION (round 8). Seven measured structures say:
// the 270us floor is insensitive to sync style, spill, and dataflow, and gets
// WORSE whenever per-SIMD independent work drops (R4/R7: per-kk operand fetch
// at 2 waves/SIMD -> 405-419us; R2: one 16-wave block serializing 4 row-groups
// -> 350us). Surviving hypothesis: per-wave latency chains + wave coupling
// (barrier convoys every 16KB tile) starve the SIMDs. This version removes ALL
// wave coupling: no gload_lds, no dbuf, no in-loop barriers; each wave owns 16
// z-rows (32-reg zf, R0's proven fragment) and streams its split's 32 tiles
// straight from global (1MB codebook, L2/L3-hot; 16 coalesced ~1KB loads per
// tile, issued back-to-back by the unrolled loop = 16 outstanding per wave).
// 8-wave blocks x (256,2) grid = 4096 independent waves, LDS only 4KB ->
// residency bounded by VGPR (~5-6 waves/SIMD of uncorrelated streams).
// NSPLIT=2 halves z re-reads and refine's pool to 6 (argmin containment: the
// global min and any fp32-tied partner are always in their split's top-3).
// Per-split visit order & ins3 tie semantics = R0's exactly.
__global__ __attribute__((amdgpu_flat_work_group_size(512, 512)))
void vq_cand_kernel(const float* __restrict__ z, const char* __restrict__ ebf_p,
                    const float* __restrict__ e2, float* __restrict__ cand_v,
                    u16* __restrict__ cand_i, int N) {
    __shared__ float e2s[1024];
    const int t    = threadIdx.x;
    const int w    = t >> 6;        // wave 0..7
    const int lane = t & 63;
    const int quad = lane >> 4;
    const int l15  = lane & 15;
    const int s    = blockIdx.y;
    const int rw   = blockIdx.x * ROWS_PER_BLOCK + w * 16;   // this wave's 16 rows

    // e2 for this split -> LDS once (512 threads x 2 floats)
    e2s[t]       = e2[s * 1024 + t];
    e2s[t + 512] = e2[s * 1024 + 512 + t];

    // ---- persistent z fragments: 16 rows x 256 dims per wave (32 VGPRs) ----
    short8v zf[8];
    {
        const float* zr = &z[(size_t)(rw + l15) * DDIM];
        #pragma unroll
        for (int kk = 0; kk < 8; ++kk) {
            int d0 = kk * 32 + quad * 8;
            float4 f0 = *(const float4*)&zr[d0];
            float4 f1 = *(const float4*)&zr[d0 + 4];
            short8v v;
            v[0] = f2bf(f0.x); v[1] = f2bf(f0.y); v[2] = f2bf(f0.z); v[3] = f2bf(f0.w);
            v[4] = f2bf(f1.x); v[5] = f2bf(f1.y); v[6] = f2bf(f1.z); v[7] = f2bf(f1.w);
            zf[kk] = v;
        }
    }

    __syncthreads();   // e2s ready; the ONLY barrier in this kernel

    float v0 = 3.4e38f, v1 = 3.4e38f, v2 = 3.4e38f;
    int   i0 = 0x7fff,  i1 = 0x7fff,  i2 = 0x7fff;

    const char* sbase = ebf_p + (size_t)s * TILES_PER_SPLIT * TILE_BYTES
                      + quad * 512 + l15 * 16;

    // ---- 32 tiles streamed from global/L2, zero synchronization ----
    #pragma unroll 1
    for (int tt = 0; tt < TILES_PER_SPLIT; ++tt) {
        const char* tg = sbase + (size_t)tt * TILE_BYTES;

        float4v acc0 = (float4v)0.0f, acc1 = (float4v)0.0f;

        #pragma unroll
        for (int kk = 0; kk < 8; ++kk) {
            short8v a0 = *(const short8v*)(tg + kk * 2048);        // codes 0..15
            short8v a1 = *(const short8v*)(tg + kk * 2048 + 256);  // codes 16..31
            acc0 = __builtin_amdgcn_mfma_f32_16x16x32_bf16(a0, zf[kk], acc0, 0, 0, 0);
            acc1 = __builtin_amdgcn_mfma_f32_16x16x32_bf16(a1, zf[kk], acc1, 0, 0, 0);
        }

        // epilogue: fold tile scores m(k)=e2[k]-2S into per-row top-3
        // (R0's exact per-row visit order -> identical tie behavior)
        const int kloc  = tt * TILE_CODES;
        const int kbase = s * 1024 + kloc;
        float4 e2a = *(const float4*)&e2s[kloc + quad * 4];
        float4 e2b = *(const float4*)&e2s[kloc + 16 + quad * 4];
        float m;
        m = fmaf(-2.0f, acc0[0], e2a.x); ins3(m, kbase + quad * 4 + 0,      v0, v1, v2, i0, i1, i2);
        m = fmaf(-2.0f, acc1[0], e2b.x); ins3(m, kbase + 16 + quad * 4 + 0, v0, v1, v2, i0, i1, i2);
        m = fmaf(-2.0f, acc0[1], e2a.y); ins3(m, kbase + quad * 4 + 1,      v0, v1, v2, i0, i1, i2);
        m = fmaf(-2.0f, acc1[1], e2b.y); ins3(m, kbase + 16 + quad * 4 + 1, v0, v1, v2, i0, i1, i2);
        m = fmaf(-2.0f, acc0[2], e2a.z); ins3(m, kbase + quad * 4 + 2,      v0, v1, v2, i0, i1, i2);
        m = fmaf(-2.0f, acc1[2], e2b.z); ins3(m, kbase + 16 + quad * 4 + 2, v0, v1, v2, i0, i1, i2);
        m = fmaf(-2.0f, acc0[3], e2a.w); ins3(m, kbase + quad * 4 + 3,      v0, v1, v2, i0, i1, i2);
        m = fmaf(-2.0f, acc1[3], e2b.w); ins3(m, kbase + 16 + quad * 4 + 3, v0, v1, v2, i0, i1, i2);
    }

    // ---- cross-quad merge via shuffles: 4 quads x top-3 -> split top-3 ----
    {
        float bm0 = 3.4e38f, bm1 = 3.4e38f, bm2 = 3.4e38f;
        int   bk0 = 0x7fff,  bk1 = 0x7fff,  bk2 = 0x7fff;
        #pragma unroll
        for (int q = 0; q < 4; ++q) {
            int src = l15 + q * 16;
            float m0 = __shfl(v0, src); int k0 = __shfl(i0, src);
            float m1 = __shfl(v1, src); int k1 = __shfl(i1, src);
            float m2 = __shfl(v2, src); int k2 = __shfl(i2, src);
            ins3(m0, k0, bm0, bm1, bm2, bk0, bk1, bk2);
            ins3(m1, k1, bm0, bm1, bm2, bk0, bk1, bk2);
            ins3(m2, k2, bm0, bm1, bm2, bk0, bk1, bk2);
        }
        // split-major layout cand[s][n][3]: contiguous per-block writes
        if (quad == 0) {
            size_t base = ((size_t)s * N + (rw + l15)) * 3;
            cand_v[base]     = bm0;  cand_i[base]     = (u16)bk0;
            cand_v[base + 1] = bm1;  cand_i[base + 1] = (u16)bk1;
            cand_v[base + 2] = bm2;  cand_i[base + 2] = (u16)bk2;
        }
    }
}

// ---------------- kernel 4: prefilter + np-faithful re-rank + gather + loss ----------------
// One wave per row. Pool = 6 (2 splits x top-3) sorted by (value,idx); exact
// fp64 dots on 6, numpy-fp32-faithful distance ranking, fused gather+partials.
__global__ void refine_fused_kernel(const float* __restrict__ z, const float* __restrict__ e,
                                    const float* __restrict__ e2np,
                                    const float* __restrict__ cand_v,
                                    const u16* __restrict__ cand_i,
                                    int* __restrict__ counts, float* __restrict__ partials,
                                    float* __restrict__ out_zq, float* __restrict__ out_idx,
                                    int N) {
    __shared__ float buf[4][DDIM];
    __shared__ float ch[4][16];
    __shared__ float wsum[4];
    const int w = threadIdx.x >> 6;
    const int t = threadIdx.x & 63;
    const int n = blockIdx.x * 4 + w;

    float4 zv = *(const float4*)&z[(size_t)n * DDIM + t * 4];
    *(float4*)&buf[w][t * 4] = zv;
    __syncthreads();
    if (t < 16) ch[w][t] = np_sq_chain(buf[w], t);
    __syncthreads();

    // ---- pool: 6 candidates, (value,idx)-sorted insertion ----
    float bv[6]; int bi[6];
    #pragma unroll
    for (int c = 0; c < 6; ++c) { bv[c] = 3.4e38f; bi[c] = 0x7fffffff; }
    #pragma unroll
    for (int c = 0; c < 6; ++c) {
        int sp = c / 3, j = c - sp * 3;
        size_t off = ((size_t)sp * N + n) * 3 + j;
        float v  = cand_v[off];
        int   id = (int)cand_i[off];
        #pragma unroll
        for (int x = 0; x < 6; ++x) {
            if (v < bv[x] || (v == bv[x] && id < bi[x])) {
                for (int d = 5; d > x; --d) { bv[d] = bv[d - 1]; bi[d] = bi[d - 1]; }
                bv[x] = v; bi[x] = id;
                break;
            }
        }
    }

    float dotf[6];
    #pragma unroll
    for (int c = 0; c < 6; ++c) {
        int k = bi[c];
        float4 ev = *(const float4*)&e[(size_t)k * DDIM + t * 4];
        double p = (double)zv.x * (double)ev.x + (double)zv.y * (double)ev.y
                 + (double)zv.z * (double)ev.z + (double)zv.w * (double)ev.w;
        #pragma unroll
        for (int o = 32; o > 0; o >>= 1) p += __shfl_down(p, o);
        dotf[c] = (float)p;   // correctly-rounded fp32 of exact dot
    }

    int bk = 0;
    if (t == 0) {
        #pragma clang fp contract(off)
        float sx = np_combine16(ch[w]);
        float bd = 3.4e38f;
        bk = 0x7fffffff;
        #pragma unroll
        for (int c = 0; c < 6; ++c) {
            float twod = 2.0f * dotf[c];
            float t1 = sx - twod;
            float d2v = t1 + e2np[bi[c]];
            d2v = fmaxf(d2v, 0.0f);
            float d = sqrtf(d2v);
            if (d < bd || (d == bd && bi[c] < bk)) { bd = d; bk = bi[c]; }
        }
    }
    int wk = __shfl(bk, 0);

    float4 ev = *(const float4*)&e[(size_t)wk * DDIM + t * 4];
    *(float4*)&out_zq[(size_t)n * DDIM + t * 4] = ev;
    float dx = zv.x - ev.x, dy = zv.y - ev.y, dz = zv.z - ev.z, dw = zv.w - ev.w;
    float sq = dx * dx + dy * dy + dz * dz + dw * dw;
    #pragma unroll
    for (int o = 32; o > 0; o >>= 1) sq += __shfl_down(sq, o);
    if (t == 0) {
        wsum[w] = sq;
        atomicAdd(&counts[wk], 1);
        out_idx[n] = (float)wk;
    }
    __syncthreads();
    if (threadIdx.x == 0)
        partials[blockIdx.x] = wsum[0] + wsum[1] + wsum[2] + wsum[3];
}

// ---------------- kernel 5: finalize loss ----------------
__global__ void finalize_kernel(const int* __restrict__ counts, const float* __restrict__ partials,
                                float* __restrict__ out_loss, int K, int NB,
                                float invN, float invND) {
    int t = threadIdx.x;
    double ent = 0.0, sq = 0.0;
    for (int k = t; k < K; k += 256) {
        float p = (float)counts[k] * invN;
        ent += (double)(p * logf(p + 1e-10f));
    }
    for (int i = t; i < NB; i += 256) sq += (double)partials[i];
    #pragma unroll
    for (int o = 32; o > 0; o >>= 1) {
        ent += __shfl_down(ent, o);
        sq  += __shfl_down(sq, o);
    }
    __shared__ double e4[4], s4[4];
    if ((t & 63) == 0) { e4[t >> 6] = ent; s4[t >> 6] = sq; }
    __syncthreads();
    if (t == 0) {
        double esum = e4[0] + e4[1] + e4[2] + e4[3];
        double ssum = s4[0] + s4[1] + s4[2] + s4[3];
        float perp = expf((float)(-esum));
        float mean = (float)ssum * invND;
        out_loss[0] = 1.25f * mean - 0.01f * perp;
    }
}

extern "C" void kernel_launch(void* const* d_in, const int* in_sizes, int n_in,
                              void* d_out, int out_size, void* d_ws, size_t ws_size,
                              hipStream_t stream) {
    const float* z = (const float*)d_in[0];
    const float* e = (const float*)d_in[1];
    const int N = in_sizes[0] / DDIM;   // 32768
    const int K = in_sizes[1] / DDIM;   // 2048

    float* out      = (float*)d_out;
    float* out_zq   = out;
    float* out_loss = out + (size_t)N * DDIM;
    float* out_idx  = out_loss + 1;

    // ws layout (bytes):
    //   counts[K]            @ 0        (8 KB)
    //   e2np[K]              @ 8192     (8 KB)
    //   partials[N/4]        @ 16384    (32 KB)
    //   cand_v[2][N][3] f32  @ 49152    (768 KB)
    //   cand_i[2][N][3] u16  @ 835584   (384 KB)
    //   ebf_p (1 MB panels)  @ 1228800  -> total ~2.2 MB
    int*   counts   = (int*)d_ws;
    float* e2np     = (float*)((char*)d_ws + 8192);
    float* partials = (float*)((char*)d_ws + 16384);
    float* cand_v   = (float*)((char*)d_ws + 49152);
    u16*   cand_i   = (u16*)((char*)d_ws + 835584);
    char*  ebf_p    = (char*)d_ws + 1228800;

    code_norms_np_kernel<<<K, 64, 0, stream>>>(e, e2np, counts);
    convert_permute_e_kernel<<<K * 32 / 256, 256, 0, stream>>>(e, ebf_p);
    vq_cand_kernel<<<dim3(N / ROWS_PER_BLOCK, NSPLIT), 512, 0, stream>>>(z, ebf_p, e2np,
                                                                         cand_v, cand_i, N);
    refine_fused_kernel<<<N / 4, 256, 0, stream>>>(z, e, e2np, cand_v, cand_i,
                                                   counts, partials, out_zq, out_idx, N);
    finalize_kernel<<<1, 256, 0, stream>>>(counts, partials, out_loss, K, N / 4,
                                           1.0f / (float)N, 1.0f / (float)(N * DDIM));
}

// Round 9
// 403.062 us; speedup vs baseline: 1.4110x; 1.0033x over previous
//
#include <hip/hip_runtime.h>
#include <math.h>

#define DDIM 256
#define NSPLIT 2
#define TILES_PER_SPLIT 32   // 32 tiles x 32 codes = 1024 codes per split
#define TILE_CODES 32
#define TILE_BYTES 16384     // 32 codes x 256 dims x 2B (panel layout)
#define ROWS_PER_BLOCK 128   // 8 waves x 16 rows

typedef __attribute__((ext_vector_type(8))) short short8v;
typedef __attribute__((ext_vector_type(4))) float float4v;
typedef unsigned int u32;
typedef unsigned short u16;

// ---- RNE float -> bf16 ----
__device__ __forceinline__ short f2bf(float x) {
    u32 u = __float_as_uint(x);
    u = u + 0x7fffu + ((u >> 16) & 1u);
    return (short)(u >> 16);
}

// ---- numpy pairwise-sum simulation (bit-faithful for n=256 contiguous) ----
__device__ __forceinline__ float np_sq_chain(const float* v, int lane) {
    #pragma clang fp contract(off)
    const int half = lane >> 3, j = lane & 7;
    const float* base = v + half * 128 + j;
    float x = base[0];
    float c = x * x;
    #pragma unroll
    for (int m = 1; m < 16; ++m) {
        float y = base[8 * m];
        float s = y * y;
        c = c + s;
    }
    return c;
}

__device__ __forceinline__ float np_combine16(const float* c) {
    #pragma clang fp contract(off)
    float L = ((c[0] + c[1]) + (c[2] + c[3])) + ((c[4] + c[5]) + (c[6] + c[7]));
    float R = ((c[8] + c[9]) + (c[10] + c[11])) + ((c[12] + c[13]) + (c[14] + c[15]));
    return L + R;
}

// ---- top-3 insertion (strict <, preserves first-insertion on ties) ----
__device__ __forceinline__ void ins3(float m, int k,
                                     float& v0, float& v1, float& v2,
                                     int& i0, int& i1, int& i2) {
    if (m < v0)      { v2 = v1; i2 = i1; v1 = v0; i1 = i0; v0 = m; i0 = k; }
    else if (m < v1) { v2 = v1; i2 = i1; v1 = m;  i1 = k; }
    else if (m < v2) { v2 = m;  i2 = k; }
}

// ---------------- kernel 2: numpy-faithful code norms ||e_k||^2 (+ zero counts) ----------------
__global__ void code_norms_np_kernel(const float* __restrict__ e, float* __restrict__ e2,
                                     int* __restrict__ counts) {
    __shared__ float buf[DDIM];
    __shared__ float ch[16];
    int k = blockIdx.x;
    int t = threadIdx.x;  // 64 threads = 1 wave
    if (t == 0) counts[k] = 0;   // fused zero_counts (grid == K)
    float4 v = *(const float4*)&e[(size_t)k * DDIM + t * 4];
    *(float4*)&buf[t * 4] = v;
    __syncthreads();
    if (t < 16) ch[t] = np_sq_chain(buf, t);
    __syncthreads();
    if (t == 0) e2[k] = np_combine16(ch);
}

// ---------------- kernel 2b: convert e -> bf16 panel layout ----------------
// ebf_p[tile=k/32][d8=0..31][r=k%32][8 shorts]; tile = 16KB contiguous.
__global__ void convert_permute_e_kernel(const float* __restrict__ e, char* __restrict__ ebf_p) {
    int id = blockIdx.x * 256 + threadIdx.x;   // id = k*32 + d8, total K*32
    int k = id >> 5, d8 = id & 31;
    const float* s = &e[(size_t)k * DDIM + d8 * 8];
    float4 f0 = *(const float4*)s;
    float4 f1 = *(const float4*)(s + 4);
    short8v v;
    v[0] = f2bf(f0.x); v[1] = f2bf(f0.y); v[2] = f2bf(f0.z); v[3] = f2bf(f0.w);
    v[4] = f2bf(f1.x); v[5] = f2bf(f1.y); v[6] = f2bf(f1.z); v[7] = f2bf(f1.w);
    *(short8v*)(ebf_p + ((size_t)(k >> 5) << 14) + d8 * 512 + (k & 31) * 16) = v;
}

// ---------------- kernel 3: barrier-free streaming MFMA, NAMED-SCALAR fragments ----------------
// SCRATCH ROOT-CAUSE FIX (round 9). R8's counters cracked it: VGPR_Count=36
// for a kernel whose persistent state alone is 40+ regs, WRITE_SIZE=16MB
// (~64B/thread). Every round that declared a `short8v zf[N]` ARRAY spilled
// ~sizeof(array)/thread REGARDLESS of waves_per_eu budget (R5's (2,4) "ignored"
// because the array was assigned to scratch during lowering, not by budget
// pressure) -- guide rule #20: ext_vector aggregates the compiler fails to
// SROA go to localMem. The only array-free kernel (R7) got 88 VGPRs.
// Fix: (a) eight NAMED scalar fragments zf0..zf7 (macro-unrolled staging and
// MFMA steps -> trivially register-allocated); (b) __launch_bounds__(512,1)
// -> 512-reg budget so the per-tile code loads can also be batched for ILP.
// Structure otherwise byte-identical to R8 (best measured, passing):
// barrier-free, codes streamed from L2, NSPLIT=2, R0 visit order.
// Falsifiable: VGPR_Count 36 -> 60-120 AND WRITE_SIZE 16MB -> <=4MB.
__global__ __launch_bounds__(512, 1)
void vq_cand_kernel(const float* __restrict__ z, const char* __restrict__ ebf_p,
                    const float* __restrict__ e2, float* __restrict__ cand_v,
                    u16* __restrict__ cand_i, int N) {
    __shared__ float e2s[1024];
    const int t    = threadIdx.x;
    const int w    = t >> 6;        // wave 0..7
    const int lane = t & 63;
    const int quad = lane >> 4;
    const int l15  = lane & 15;
    const int s    = blockIdx.y;
    const int rw   = blockIdx.x * ROWS_PER_BLOCK + w * 16;   // this wave's 16 rows

    // e2 for this split -> LDS once (512 threads x 2 floats)
    e2s[t]       = e2[s * 1024 + t];
    e2s[t + 512] = e2[s * 1024 + 512 + t];

    // ---- persistent z fragments: 16 rows x 256 dims per wave, NAMED scalars ----
    short8v zf0, zf1, zf2, zf3, zf4, zf5, zf6, zf7;
    {
        const float* zr = &z[(size_t)(rw + l15) * DDIM];
#define LOADZ(I, DST)                                                        \
        {                                                                    \
            int d0 = (I) * 32 + quad * 8;                                    \
            float4 f0 = *(const float4*)&zr[d0];                             \
            float4 f1 = *(const float4*)&zr[d0 + 4];                         \
            short8v v;                                                       \
            v[0] = f2bf(f0.x); v[1] = f2bf(f0.y);                            \
            v[2] = f2bf(f0.z); v[3] = f2bf(f0.w);                            \
            v[4] = f2bf(f1.x); v[5] = f2bf(f1.y);                            \
            v[6] = f2bf(f1.z); v[7] = f2bf(f1.w);                            \
            DST = v;                                                         \
        }
        LOADZ(0, zf0) LOADZ(1, zf1) LOADZ(2, zf2) LOADZ(3, zf3)
        LOADZ(4, zf4) LOADZ(5, zf5) LOADZ(6, zf6) LOADZ(7, zf7)
#undef LOADZ
    }

    __syncthreads();   // e2s ready; the ONLY barrier in this kernel

    float v0 = 3.4e38f, v1 = 3.4e38f, v2 = 3.4e38f;
    int   i0 = 0x7fff,  i1 = 0x7fff,  i2 = 0x7fff;

    const char* sbase = ebf_p + (size_t)s * TILES_PER_SPLIT * TILE_BYTES
                      + quad * 512 + l15 * 16;

    // ---- 32 tiles streamed from global/L2, zero synchronization ----
    #pragma unroll 1
    for (int tt = 0; tt < TILES_PER_SPLIT; ++tt) {
        const char* tg = sbase + (size_t)tt * TILE_BYTES;

        float4v acc0 = (float4v)0.0f, acc1 = (float4v)0.0f;

#define STEP(KK, ZF)                                                         \
        {                                                                    \
            short8v a0 = *(const short8v*)(tg + (KK) * 2048);                \
            short8v a1 = *(const short8v*)(tg + (KK) * 2048 + 256);          \
            acc0 = __builtin_amdgcn_mfma_f32_16x16x32_bf16(a0, ZF, acc0, 0, 0, 0); \
            acc1 = __builtin_amdgcn_mfma_f32_16x16x32_bf16(a1, ZF, acc1, 0, 0, 0); \
        }
        STEP(0, zf0) STEP(1, zf1) STEP(2, zf2) STEP(3, zf3)
        STEP(4, zf4) STEP(5, zf5) STEP(6, zf6) STEP(7, zf7)
#undef STEP

        // epilogue: fold tile scores m(k)=e2[k]-2S into per-row top-3
        // (R0's exact per-row visit order -> identical tie behavior)
        const int kloc  = tt * TILE_CODES;
        const int kbase = s * 1024 + kloc;
        float4 e2a = *(const float4*)&e2s[kloc + quad * 4];
        float4 e2b = *(const float4*)&e2s[kloc + 16 + quad * 4];
        float m;
        m = fmaf(-2.0f, acc0[0], e2a.x); ins3(m, kbase + quad * 4 + 0,      v0, v1, v2, i0, i1, i2);
        m = fmaf(-2.0f, acc1[0], e2b.x); ins3(m, kbase + 16 + quad * 4 + 0, v0, v1, v2, i0, i1, i2);
        m = fmaf(-2.0f, acc0[1], e2a.y); ins3(m, kbase + quad * 4 + 1,      v0, v1, v2, i0, i1, i2);
        m = fmaf(-2.0f, acc1[1], e2b.y); ins3(m, kbase + 16 + quad * 4 + 1, v0, v1, v2, i0, i1, i2);
        m = fmaf(-2.0f, acc0[2], e2a.z); ins3(m, kbase + quad * 4 + 2,      v0, v1, v2, i0, i1, i2);
        m = fmaf(-2.0f, acc1[2], e2b.z); ins3(m, kbase + 16 + quad * 4 + 2, v0, v1, v2, i0, i1, i2);
        m = fmaf(-2.0f, acc0[3], e2a.w); ins3(m, kbase + quad * 4 + 3,      v0, v1, v2, i0, i1, i2);
        m = fmaf(-2.0f, acc1[3], e2b.w); ins3(m, kbase + 16 + quad * 4 + 3, v0, v1, v2, i0, i1, i2);
    }

    // ---- cross-quad merge via shuffles: 4 quads x top-3 -> split top-3 ----
    {
        float bm0 = 3.4e38f, bm1 = 3.4e38f, bm2 = 3.4e38f;
        int   bk0 = 0x7fff,  bk1 = 0x7fff,  bk2 = 0x7fff;
        #pragma unroll
        for (int q = 0; q < 4; ++q) {
            int src = l15 + q * 16;
            float m0 = __shfl(v0, src); int k0 = __shfl(i0, src);
            float m1 = __shfl(v1, src); int k1 = __shfl(i1, src);
            float m2 = __shfl(v2, src); int k2 = __shfl(i2, src);
            ins3(m0, k0, bm0, bm1, bm2, bk0, bk1, bk2);
            ins3(m1, k1, bm0, bm1, bm2, bk0, bk1, bk2);
            ins3(m2, k2, bm0, bm1, bm2, bk0, bk1, bk2);
        }
        // split-major layout cand[s][n][3]: contiguous per-block writes
        if (quad == 0) {
            size_t base = ((size_t)s * N + (rw + l15)) * 3;
            cand_v[base]     = bm0;  cand_i[base]     = (u16)bk0;
            cand_v[base + 1] = bm1;  cand_i[base + 1] = (u16)bk1;
            cand_v[base + 2] = bm2;  cand_i[base + 2] = (u16)bk2;
        }
    }
}

// ---------------- kernel 4: prefilter + np-faithful re-rank + gather + loss ----------------
// One wave per row. Pool = 6 (2 splits x top-3) sorted by (value,idx); exact
// fp64 dots on 6, numpy-fp32-faithful distance ranking, fused gather+partials.
__global__ void refine_fused_kernel(const float* __restrict__ z, const float* __restrict__ e,
                                    const float* __restrict__ e2np,
                                    const float* __restrict__ cand_v,
                                    const u16* __restrict__ cand_i,
                                    int* __restrict__ counts, float* __restrict__ partials,
                                    float* __restrict__ out_zq, float* __restrict__ out_idx,
                                    int N) {
    __shared__ float buf[4][DDIM];
    __shared__ float ch[4][16];
    __shared__ float wsum[4];
    const int w = threadIdx.x >> 6;
    const int t = threadIdx.x & 63;
    const int n = blockIdx.x * 4 + w;

    float4 zv = *(const float4*)&z[(size_t)n * DDIM + t * 4];
    *(float4*)&buf[w][t * 4] = zv;
    __syncthreads();
    if (t < 16) ch[w][t] = np_sq_chain(buf[w], t);
    __syncthreads();

    // ---- pool: 6 candidates, (value,idx)-sorted insertion ----
    float bv[6]; int bi[6];
    #pragma unroll
    for (int c = 0; c < 6; ++c) { bv[c] = 3.4e38f; bi[c] = 0x7fffffff; }
    #pragma unroll
    for (int c = 0; c < 6; ++c) {
        int sp = c / 3, j = c - sp * 3;
        size_t off = ((size_t)sp * N + n) * 3 + j;
        float v  = cand_v[off];
        int   id = (int)cand_i[off];
        #pragma unroll
        for (int x = 0; x < 6; ++x) {
            if (v < bv[x] || (v == bv[x] && id < bi[x])) {
                for (int d = 5; d > x; --d) { bv[d] = bv[d - 1]; bi[d] = bi[d - 1]; }
                bv[x] = v; bi[x] = id;
                break;
            }
        }
    }

    float dotf[6];
    #pragma unroll
    for (int c = 0; c < 6; ++c) {
        int k = bi[c];
        float4 ev = *(const float4*)&e[(size_t)k * DDIM + t * 4];
        double p = (double)zv.x * (double)ev.x + (double)zv.y * (double)ev.y
                 + (double)zv.z * (double)ev.z + (double)zv.w * (double)ev.w;
        #pragma unroll
        for (int o = 32; o > 0; o >>= 1) p += __shfl_down(p, o);
        dotf[c] = (float)p;   // correctly-rounded fp32 of exact dot
    }

    int bk = 0;
    if (t == 0) {
        #pragma clang fp contract(off)
        float sx = np_combine16(ch[w]);
        float bd = 3.4e38f;
        bk = 0x7fffffff;
        #pragma unroll
        for (int c = 0; c < 6; ++c) {
            float twod = 2.0f * dotf[c];
            float t1 = sx - twod;
            float d2v = t1 + e2np[bi[c]];
            d2v = fmaxf(d2v, 0.0f);
            float d = sqrtf(d2v);
            if (d < bd || (d == bd && bi[c] < bk)) { bd = d; bk = bi[c]; }
        }
    }
    int wk = __shfl(bk, 0);

    float4 ev = *(const float4*)&e[(size_t)wk * DDIM + t * 4];
    *(float4*)&out_zq[(size_t)n * DDIM + t * 4] = ev;
    float dx = zv.x - ev.x, dy = zv.y - ev.y, dz = zv.z - ev.z, dw = zv.w - ev.w;
    float sq = dx * dx + dy * dy + dz * dz + dw * dw;
    #pragma unroll
    for (int o = 32; o > 0; o >>= 1) sq += __shfl_down(sq, o);
    if (t == 0) {
        wsum[w] = sq;
        atomicAdd(&counts[wk], 1);
        out_idx[n] = (float)wk;
    }
    __syncthreads();
    if (threadIdx.x == 0)
        partials[blockIdx.x] = wsum[0] + wsum[1] + wsum[2] + wsum[3];
}

// ---------------- kernel 5: finalize loss ----------------
__global__ void finalize_kernel(const int* __restrict__ counts, const float* __restrict__ partials,
                                float* __restrict__ out_loss, int K, int NB,
                                float invN, float invND) {
    int t = threadIdx.x;
    double ent = 0.0, sq = 0.0;
    for (int k = t; k < K; k += 256) {
        float p = (float)counts[k] * invN;
        ent += (double)(p * logf(p + 1e-10f));
    }
    for (int i = t; i < NB; i += 256) sq += (double)partials[i];
    #pragma unroll
    for (int o = 32; o > 0; o >>= 1) {
        ent += __shfl_down(ent, o);
        sq  += __shfl_down(sq, o);
    }
    __shared__ double e4[4], s4[4];
    if ((t & 63) == 0) { e4[t >> 6] = ent; s4[t >> 6] = sq; }
    __syncthreads();
    if (t == 0) {
        double esum = e4[0] + e4[1] + e4[2] + e4[3];
        double ssum = s4[0] + s4[1] + s4[2] + s4[3];
        float perp = expf((float)(-esum));
        float mean = (float)ssum * invND;
        out_loss[0] = 1.25f * mean - 0.01f * perp;
    }
}

extern "C" void kernel_launch(void* const* d_in, const int* in_sizes, int n_in,
                              void* d_out, int out_size, void* d_ws, size_t ws_size,
                              hipStream_t stream) {
    const float* z = (const float*)d_in[0];
    const float* e = (const float*)d_in[1];
    const int N = in_sizes[0] / DDIM;   // 32768
    const int K = in_sizes[1] / DDIM;   // 2048

    float* out      = (float*)d_out;
    float* out_zq   = out;
    float* out_loss = out + (size_t)N * DDIM;
    float* out_idx  = out_loss + 1;

    // ws layout (bytes):
    //   counts[K]            @ 0        (8 KB)
    //   e2np[K]              @ 8192     (8 KB)
    //   partials[N/4]        @ 16384    (32 KB)
    //   cand_v[2][N][3] f32  @ 49152    (768 KB)
    //   cand_i[2][N][3] u16  @ 835584   (384 KB)
    //   ebf_p (1 MB panels)  @ 1228800  -> total ~2.2 MB
    int*   counts   = (int*)d_ws;
    float* e2np     = (float*)((char*)d_ws + 8192);
    float* partials = (float*)((char*)d_ws + 16384);
    float* cand_v   = (float*)((char*)d_ws + 49152);
    u16*   cand_i   = (u16*)((char*)d_ws + 835584);
    char*  ebf_p    = (char*)d_ws + 1228800;

    code_norms_np_kernel<<<K, 64, 0, stream>>>(e, e2np, counts);
    convert_permute_e_kernel<<<K * 32 / 256, 256, 0, stream>>>(e, ebf_p);
    vq_cand_kernel<<<dim3(N / ROWS_PER_BLOCK, NSPLIT), 512, 0, stream>>>(z, ebf_p, e2np,
                                                                         cand_v, cand_i, N);
    refine_fused_kernel<<<N / 4, 256, 0, stream>>>(z, e, e2np, cand_v, cand_i,
                                                   counts, partials, out_zq, out_idx, N);
    finalize_kernel<<<1, 256, 0, stream>>>(counts, partials, out_loss, K, N / 4,
                                           1.0f / (float)N, 1.0f / (float)(N * DDIM));
}